// Round 5
// baseline (33332.227 us; speedup 1.0000x reference)
//
#include <hip/hip_runtime.h>
#include <hip/hip_bf16.h>

using bf16   = __bf16;
using bf16x8 = __attribute__((ext_vector_type(8))) __bf16;
using f32x4  = __attribute__((ext_vector_type(4))) float;
using u32x4  = __attribute__((ext_vector_type(4))) unsigned int;

#define TSTEPS 255
// element (bf16) counts
#define UNITE  512              // elements per 1KiB MFMA fragment unit
#define HPAR   (16*16*512)      // one (parity,hi-or-lo) h plane: 16 bq x 16 kb units
#define WA_UNITS_DIR (128*24)
#define WB_UNITS_DIR (128*32)
#define WC_UNITS_DIR (16*16)

#define MFMA(acc, a, b) acc = __builtin_amdgcn_mfma_f32_16x16x32_bf16((a), (b), (acc), 0, 0, 0)

__device__ __forceinline__ float sigmoidf_(float x) { return 1.f / (1.f + __expf(-x)); }
__device__ __forceinline__ float tanhf_(float x) {
    float e = __expf(-2.f * fabsf(x));
    float t = (1.f - e) / (1.f + e);
    return copysignf(t, x);
}

// Write-through coherent 2B store pair (hi, lo). sc0 sc1 -> store goes to the
// device coherent point (IC) directly, never dirty in producer L2 -> barrier
// release needs only s_waitcnt vmcnt(0), no buffer_wbl2. Also: no L2 pollution.
__device__ __forceinline__ void storeh_coh(bf16* ph, bf16* pl,
                                           unsigned short vh, unsigned short vl) {
    asm volatile(
        "global_store_short %0, %2, off sc0 sc1\n\t"
        "global_store_short %1, %3, off sc0 sc1"
        :: "v"(ph), "v"(pl), "v"(vh), "v"(vl)
        : "memory");
}

// Coherent 32KiB global->LDS stage (hi 16KiB + lo 16KiB), 256 threads.
// 8 dwordx4 loads per thread issued back-to-back (8-deep MLP), one waitcnt,
// then LDS writes. global_load imm offset is 13-bit signed -> per-round bases.
__device__ __forceinline__ void stage32k(const bf16* gh, const bf16* gl,
                                         bf16* lds, int tid) {
    u32x4 a0, a1, a2, a3, b0, b1, b2, b3;
    const bf16* p0 = gh + tid * 8;
    const bf16* p1 = p0 + 2048;       // +4096 B
    const bf16* p2 = p0 + 4096;       // +8192 B
    const bf16* p3 = p0 + 6144;       // +12288 B
    const bf16* q0 = gl + tid * 8;
    const bf16* q1 = q0 + 2048;
    const bf16* q2 = q0 + 4096;
    const bf16* q3 = q0 + 6144;
    asm volatile(
        "global_load_dwordx4 %0, %8, off sc0 sc1\n\t"
        "global_load_dwordx4 %1, %9, off sc0 sc1\n\t"
        "global_load_dwordx4 %2, %10, off sc0 sc1\n\t"
        "global_load_dwordx4 %3, %11, off sc0 sc1\n\t"
        "global_load_dwordx4 %4, %12, off sc0 sc1\n\t"
        "global_load_dwordx4 %5, %13, off sc0 sc1\n\t"
        "global_load_dwordx4 %6, %14, off sc0 sc1\n\t"
        "global_load_dwordx4 %7, %15, off sc0 sc1\n\t"
        "s_waitcnt vmcnt(0)"
        : "=&v"(a0), "=&v"(a1), "=&v"(a2), "=&v"(a3),
          "=&v"(b0), "=&v"(b1), "=&v"(b2), "=&v"(b3)
        : "v"(p0), "v"(p1), "v"(p2), "v"(p3),
          "v"(q0), "v"(q1), "v"(q2), "v"(q3)
        : "memory");
    *(u32x4*)(lds + tid * 8)                 = a0;   // hi plane: elements [0, 8192)
    *(u32x4*)(lds + tid * 8 + 2048)          = a1;
    *(u32x4*)(lds + tid * 8 + 4096)          = a2;
    *(u32x4*)(lds + tid * 8 + 6144)          = a3;
    *(u32x4*)(lds + 8192 + tid * 8)          = b0;   // lo plane: elements [8192, 16384)
    *(u32x4*)(lds + 8192 + tid * 8 + 2048)   = b1;
    *(u32x4*)(lds + 8192 + tid * 8 + 4096)   = b2;
    *(u32x4*)(lds + 8192 + tid * 8 + 6144)   = b3;
}

// fp32x8 -> (bf16 hi, bf16 lo) x8.  lo = rnd(v - hi).
__device__ __forceinline__ void split_store8(const float* __restrict__ src,
                                             bf16* __restrict__ dh, bf16* __restrict__ dl) {
    float f[8];
    *(float4*)f       = *(const float4*)src;
    *(float4*)(f + 4) = *(const float4*)(src + 4);
    bf16x8 oh, ol;
    #pragma unroll
    for (int j = 0; j < 8; ++j) { bf16 h = (bf16)f[j]; oh[j] = h; ol[j] = (bf16)(f[j] - (float)h); }
    *(bf16x8*)dh = oh; *(bf16x8*)dl = ol;
}

// ---------------- software grid barrier (no wbl2, no cache invalidation) ----
__device__ __forceinline__ void gbarrier(unsigned* __restrict__ flags, int bid, unsigned epoch) {
    asm volatile("s_waitcnt vmcnt(0)" ::: "memory");   // release: coherent h stores at IC
    __syncthreads();
    if (threadIdx.x == 0)
        asm volatile("global_store_dword %0, %1, off sc0 sc1"
                     :: "v"(&flags[bid]), "v"(epoch) : "memory");
    if (threadIdx.x < 64) {
        const int l = threadIdx.x;
        for (;;) {
            unsigned f0 = __hip_atomic_load(&flags[l],       __ATOMIC_RELAXED, __HIP_MEMORY_SCOPE_AGENT);
            unsigned f1 = __hip_atomic_load(&flags[l + 64],  __ATOMIC_RELAXED, __HIP_MEMORY_SCOPE_AGENT);
            unsigned f2 = __hip_atomic_load(&flags[l + 128], __ATOMIC_RELAXED, __HIP_MEMORY_SCOPE_AGENT);
            unsigned f3 = __hip_atomic_load(&flags[l + 192], __ATOMIC_RELAXED, __HIP_MEMORY_SCOPE_AGENT);
            if (__all(f0 >= epoch && f1 >= epoch && f2 >= epoch && f3 >= epoch)) break;
            __builtin_amdgcn_s_sleep(1);
        }
    }
    __syncthreads();
}

// ---------------- precompute kernels (UNCHANGED packing) ----------------

__global__ void k_pack_wa(const float* __restrict__ wihL, const float* __restrict__ whhL,
                          const float* __restrict__ wihR, const float* __restrict__ whhR,
                          bf16* __restrict__ wah, bf16* __restrict__ wal) {
    int gid = blockIdx.x * 256 + threadIdx.x;      // 393,216
    int lane = gid & 63, u = gid >> 6;             // u < 6144
    int kb = u % 24; int tn = (u / 24) & 127; int dir = u / 3072;
    int r = lane & 15, q = lane >> 4;
    int n = tn * 16 + r, k = kb * 32 + q * 8;
    const float* wih = dir ? wihR : wihL;          // layer 0 slice at offset 0
    const float* whh = dir ? whhR : whhL;
    const float* src = (k < 256) ? (wih + (size_t)n * 256 + k)
                                 : (whh + (size_t)n * 512 + (k - 256));
    split_store8(src, wah + (size_t)u * UNITE + lane * 8, wal + (size_t)u * UNITE + lane * 8);
}

__global__ void k_wcomb(const float* __restrict__ wihL, const float* __restrict__ wfcL,
                        const float* __restrict__ wihR, const float* __restrict__ wfcR,
                        float* __restrict__ wcf) {
    size_t gid = (size_t)blockIdx.x * 256 + threadIdx.x;  // 2,097,152
    int k = gid & 511; int n = (gid >> 9) & 2047; int dir = (int)(gid >> 20);
    const float* wih1 = (dir ? wihR : wihL) + (size_t)2048 * 256;  // layer 1
    const float* wfc0 = (dir ? wfcR : wfcL);                        // layer 0
    float s = 0.f;
    #pragma unroll 8
    for (int v = 0; v < 256; ++v)
        s = fmaf(wih1[(size_t)n * 256 + v], wfc0[(size_t)v * 512 + k], s);
    wcf[gid] = s;
}

__global__ void k_pack_wb(const float* __restrict__ whhL, const float* __restrict__ whhR,
                          const float* __restrict__ wcf,
                          bf16* __restrict__ wbh, bf16* __restrict__ wbl) {
    int gid = blockIdx.x * 256 + threadIdx.x;      // 524,288
    int lane = gid & 63, u = gid >> 6;             // u < 8192
    int kb = u & 31, tn = (u >> 5) & 127, dir = u >> 12;
    int r = lane & 15, q = lane >> 4;
    int n = tn * 16 + r, k = kb * 32 + q * 8;
    const float* src;
    if (k < 512) {
        src = wcf + ((size_t)dir * 2048 + n) * 512 + k;
    } else {
        const float* whh1 = (dir ? whhR : whhL) + (size_t)2048 * 512;
        src = whh1 + (size_t)n * 512 + (k - 512);
    }
    split_store8(src, wbh + (size_t)u * UNITE + lane * 8, wbl + (size_t)u * UNITE + lane * 8);
}

__global__ void k_pack_wc(const float* __restrict__ wfcL, const float* __restrict__ wfcR,
                          bf16* __restrict__ wch, bf16* __restrict__ wcl) {
    int gid = blockIdx.x * 256 + threadIdx.x;      // 32,768
    int lane = gid & 63, u = gid >> 6;             // u < 512
    int kb = u & 15, tn = (u >> 4) & 15, dir = u >> 8;
    int r = lane & 15, q = lane >> 4;
    int n = tn * 16 + r, k = kb * 32 + q * 8;
    const float* wfc1 = (dir ? wfcR : wfcL) + (size_t)256 * 512;   // layer 1
    split_store8(wfc1 + (size_t)n * 512 + k,
                 wch + (size_t)u * UNITE + lane * 8, wcl + (size_t)u * UNITE + lane * 8);
}

__global__ void k_bias(const float* __restrict__ bihL, const float* __restrict__ bhhL,
                       const float* __restrict__ bfcL, const float* __restrict__ wihL,
                       const float* __restrict__ bihR, const float* __restrict__ bhhR,
                       const float* __restrict__ bfcR, const float* __restrict__ wihR,
                       float* __restrict__ ba, float* __restrict__ bb, float* __restrict__ bc) {
    int gid = blockIdx.x * 256 + threadIdx.x;      // 4096
    int n = gid & 2047, dir = gid >> 11;
    const float* bih = dir ? bihR : bihL;
    const float* bhh = dir ? bhhR : bhhL;
    const float* bfc = dir ? bfcR : bfcL;
    const float* wih1 = (dir ? wihR : wihL) + (size_t)2048 * 256;
    ba[dir * 2048 + n] = bih[n] + bhh[n];
    float s = bih[2048 + n] + bhh[2048 + n];
    #pragma unroll 8
    for (int v = 0; v < 256; ++v)
        s = fmaf(bfc[v], wih1[(size_t)n * 256 + v], s);
    bb[dir * 2048 + n] = s;
    if (n < 256) bc[dir * 256 + n] = bfc[256 + n];
}

// ---------------- main persistent kernel ----------------
// Decomposition (R2/R3): block = (dir, nslc in 0..7, bq in 0..15).
// R4 change: ALL zero-L2-reuse streams are non-polluting so the per-XCD
// ~3.66 MiB weight slice stays L2-resident:
//   - x loads:   __builtin_nontemporal_load  (nt: evict-first, x has 0 reuse)
//   - out stores: __builtin_nontemporal_store (nt: each line written once)
//   - h reads/writes + flags: already sc0 sc1 (L2-bypassing coherent)
// R3's FETCH (22.9 GB) ~= weight slice refetched ~2.4x/phase from IC: L2
// (4 MiB) thrashes because weights (3.66 MiB) + streaming x/out just exceed
// capacity. With nt streams, weights should hit L2 ~always.
__global__ __launch_bounds__(256) void bilstm_main(
    const float* __restrict__ x,
    const bf16* __restrict__ wah, const bf16* __restrict__ wal,
    const bf16* __restrict__ wbh, const bf16* __restrict__ wbl,
    const bf16* __restrict__ wch, const bf16* __restrict__ wcl,
    bf16* __restrict__ h0pk, bf16* __restrict__ h1pk,
    const float* __restrict__ ba, const float* __restrict__ bb,
    const float* __restrict__ bc, float* __restrict__ out,
    unsigned* __restrict__ flags)
{
    const int bid  = blockIdx.x;
    const int nslc = bid & 7;            // == XCD (bid%8 heuristic)
    const int bq   = (bid >> 3) & 15;    // batch-row slice
    const int dir  = bid >> 7;
    const int tid  = threadIdx.x;
    const int wv   = tid >> 6;
    const int lane = tid & 63;
    const int r = lane & 15, q = lane >> 4;

    __shared__ __align__(16) bf16 h0s[16384];   // 32 KiB: h0 slice hi[0,8192) lo[8192,16384)
    __shared__ __align__(16) bf16 h1s[16384];   // 32 KiB: h1 slice

    const bf16* WAh = wah + (size_t)dir * WA_UNITS_DIR * UNITE;
    const bf16* WAl = wal + (size_t)dir * WA_UNITS_DIR * UNITE;
    const bf16* WBh = wbh + (size_t)dir * WB_UNITS_DIR * UNITE;
    const bf16* WBl = wbl + (size_t)dir * WB_UNITS_DIR * UNITE;
    const bf16* WCh = wch + (size_t)dir * WC_UNITS_DIR * UNITE;
    const bf16* WCl = wcl + (size_t)dir * WC_UNITS_DIR * UNITE;
    bf16* H0 = h0pk + (size_t)dir * 4 * HPAR;   // [parity][hi/lo][HPAR]
    bf16* H1 = h1pk + (size_t)dir * 4 * HPAR;
    const float* BA = ba + dir * 2048;
    const float* BB = bb + dir * 2048;
    const float* BC = bc + dir * 256;

    const int nbase = nslc * 4 + wv;             // n-unit (16 gate cols) per wave
    const int col   = nslc * 64 + wv * 16 + r;   // hidden col this lane owns
    const float bia0 = BA[col], bia1 = BA[512 + col], bia2 = BA[1024 + col], bia3 = BA[1536 + col];
    const float bib0 = BB[col], bib1 = BB[512 + col], bib2 = BB[1024 + col], bib3 = BB[1536 + col];

    // h write address: unit = bq*16 + (col>>5); within-unit A-fragment offset
    const int hunit  = bq * 16 + nslc * 2 + (wv >> 1);
    const int hw_off = ((wv & 1) * 2 + (r >> 3)) * 128 + q * 32 + (r & 7);

    // y-tile: waves 0,1 compute V-cols tn*16..+15 for this block's batch rows
    const int tn  = nslc * 2 + (wv & 1);
    const float byc = BC[tn * 16 + r];

    f32x4 c0 = {0.f, 0.f, 0.f, 0.f}, c1 = {0.f, 0.f, 0.f, 0.f};
    unsigned epoch = 0;

    // zero h0s (h0 at t=-1 is zero)
    #pragma unroll
    for (int k2 = 0; k2 < 8; ++k2) *(u32x4*)(h0s + tid * 8 + k2 * 2048) = (u32x4){0, 0, 0, 0};
    __syncthreads();

    for (int t = 0; t <= TSTEPS; ++t) {
        const int pw = t & 1, pr = pw ^ 1;
        // ---- phase A: stage h1[pr] (written at t-1 phase B; zeros at t=0) ----
        stage32k(H1 + (size_t)pr * 2 * HPAR + (size_t)bq * 8192,
                 H1 + (size_t)pr * 2 * HPAR + HPAR + (size_t)bq * 8192, h1s, tid);
        // ---- phase A: gates0 + elementwise (t<255) ----
        if (t < TSTEPS) {
            const int pos = dir ? (255 - t) : t;
            f32x4 acc[4] = {{0,0,0,0},{0,0,0,0},{0,0,0,0},{0,0,0,0}};
            const float* xp = x + ((size_t)(bq * 16 + r) * 256 + pos) * 256 + q * 8;
            #pragma unroll
            for (int kb = 0; kb < 8; ++kb) {        // x part (K 0..255), nt fp32 loads
                f32x4 xa = __builtin_nontemporal_load((const f32x4*)(xp + kb * 32));
                f32x4 xb = __builtin_nontemporal_load((const f32x4*)(xp + kb * 32 + 4));
                float xf[8];
                xf[0] = xa[0]; xf[1] = xa[1]; xf[2] = xa[2]; xf[3] = xa[3];
                xf[4] = xb[0]; xf[5] = xb[1]; xf[6] = xb[2]; xf[7] = xb[3];
                bf16x8 axh, axl;
                #pragma unroll
                for (int j = 0; j < 8; ++j) { bf16 h = (bf16)xf[j]; axh[j] = h; axl[j] = (bf16)(xf[j] - (float)h); }
                #pragma unroll
                for (int g = 0; g < 4; ++g) {
                    const size_t wu = ((size_t)((g * 32 + nbase) * 24 + kb)) * UNITE + lane * 8;
                    bf16x8 bh = *(const bf16x8*)(WAh + wu);
                    bf16x8 bl = *(const bf16x8*)(WAl + wu);
                    MFMA(acc[g], axh, bh); MFMA(acc[g], axh, bl); MFMA(acc[g], axl, bh);
                }
            }
            #pragma unroll
            for (int hk = 0; hk < 16; ++hk) {       // h0(t-1) part (K 256..767), from LDS
                bf16x8 ah = *(const bf16x8*)(h0s + hk * 512 + lane * 8);
                bf16x8 al = *(const bf16x8*)(h0s + 8192 + hk * 512 + lane * 8);
                #pragma unroll
                for (int g = 0; g < 4; ++g) {
                    const size_t wu = ((size_t)((g * 32 + nbase) * 24 + 8 + hk)) * UNITE + lane * 8;
                    bf16x8 bh = *(const bf16x8*)(WAh + wu);
                    bf16x8 bl = *(const bf16x8*)(WAl + wu);
                    MFMA(acc[g], ah, bh); MFMA(acc[g], ah, bl); MFMA(acc[g], al, bh);
                }
            }
            bf16* WH = H0 + (size_t)pw * 2 * HPAR + (size_t)hunit * 512 + hw_off;
            bf16* WL = WH + HPAR;
            #pragma unroll
            for (int i = 0; i < 4; ++i) {
                float gi = sigmoidf_(acc[0][i] + bia0);
                float gf = sigmoidf_(acc[1][i] + bia1);
                float gg = tanhf_   (acc[2][i] + bia2);
                float go = sigmoidf_(acc[3][i] + bia3);
                float cc = gf * c0[i] + gi * gg;
                c0[i] = cc;
                float hv = go * tanhf_(cc);
                bf16 hh = (bf16)hv;
                bf16 hl = (bf16)(hv - (float)hh);
                storeh_coh(WH + i * 8, WL + i * 8,
                           __builtin_bit_cast(unsigned short, hh),
                           __builtin_bit_cast(unsigned short, hl));
            }
        }
        __syncthreads();   // h1s staged & visible
        // ---- phase A: y(t-1) = h1(t-1) @ wfc1^T + bfc1 (t>=1), waves 0,1 ----
        if (t >= 1 && wv < 2) {
            f32x4 accy = {0, 0, 0, 0};
            #pragma unroll
            for (int kb = 0; kb < 16; ++kb) {
                bf16x8 ah = *(const bf16x8*)(h1s + kb * 512 + lane * 8);
                bf16x8 al = *(const bf16x8*)(h1s + 8192 + kb * 512 + lane * 8);
                const size_t wu = ((size_t)(tn * 16 + kb)) * UNITE + lane * 8;
                bf16x8 bh = *(const bf16x8*)(WCh + wu);
                bf16x8 bl = *(const bf16x8*)(WCl + wu);
                MFMA(accy, ah, bh); MFMA(accy, ah, bl); MFMA(accy, al, bh);
            }
            const int tout = dir ? (255 + (t - 1)) : (t - 1);
            #pragma unroll
            for (int i = 0; i < 4; ++i)
                __builtin_nontemporal_store(accy[i] + byc,
                    out + ((size_t)(bq * 16 + 4 * q + i) * 510 + tout) * 256 + tn * 16 + r);
        }
        ++epoch; gbarrier(flags, bid, epoch);
        // ---- phase B: stage h0[pw] (just written) + gates1 + elementwise ----
        if (t < TSTEPS) {
            stage32k(H0 + (size_t)pw * 2 * HPAR + (size_t)bq * 8192,
                     H0 + (size_t)pw * 2 * HPAR + HPAR + (size_t)bq * 8192, h0s, tid);
            __syncthreads();   // h0s ready (stays valid for next step's phase A)
            f32x4 acc[4] = {{0,0,0,0},{0,0,0,0},{0,0,0,0},{0,0,0,0}};
            #pragma unroll
            for (int hk = 0; hk < 16; ++hk) {       // h0(t) part (K 0..511)
                bf16x8 ah = *(const bf16x8*)(h0s + hk * 512 + lane * 8);
                bf16x8 al = *(const bf16x8*)(h0s + 8192 + hk * 512 + lane * 8);
                #pragma unroll
                for (int g = 0; g < 4; ++g) {
                    const size_t wu = ((size_t)((g * 32 + nbase) * 32 + hk)) * UNITE + lane * 8;
                    bf16x8 bh = *(const bf16x8*)(WBh + wu);
                    bf16x8 bl = *(const bf16x8*)(WBl + wu);
                    MFMA(acc[g], ah, bh); MFMA(acc[g], ah, bl); MFMA(acc[g], al, bh);
                }
            }
            #pragma unroll
            for (int hk = 0; hk < 16; ++hk) {       // h1(t-1) part (K 512..1023)
                bf16x8 ah = *(const bf16x8*)(h1s + hk * 512 + lane * 8);
                bf16x8 al = *(const bf16x8*)(h1s + 8192 + hk * 512 + lane * 8);
                #pragma unroll
                for (int g = 0; g < 4; ++g) {
                    const size_t wu = ((size_t)((g * 32 + nbase) * 32 + 16 + hk)) * UNITE + lane * 8;
                    bf16x8 bh = *(const bf16x8*)(WBh + wu);
                    bf16x8 bl = *(const bf16x8*)(WBl + wu);
                    MFMA(acc[g], ah, bh); MFMA(acc[g], ah, bl); MFMA(acc[g], al, bh);
                }
            }
            bf16* WH = H1 + (size_t)pw * 2 * HPAR + (size_t)hunit * 512 + hw_off;
            bf16* WL = WH + HPAR;
            #pragma unroll
            for (int i = 0; i < 4; ++i) {
                float gi = sigmoidf_(acc[0][i] + bib0);
                float gf = sigmoidf_(acc[1][i] + bib1);
                float gg = tanhf_   (acc[2][i] + bib2);
                float go = sigmoidf_(acc[3][i] + bib3);
                float cc = gf * c1[i] + gi * gg;
                c1[i] = cc;
                float hv = go * tanhf_(cc);
                bf16 hh = (bf16)hv;
                bf16 hl = (bf16)(hv - (float)hh);
                storeh_coh(WH + i * 8, WL + i * 8,
                           __builtin_bit_cast(unsigned short, hh),
                           __builtin_bit_cast(unsigned short, hl));
            }
        }
        ++epoch; gbarrier(flags, bid, epoch);
    }
}

// ---------------- host launch ----------------
extern "C" void kernel_launch(void* const* d_in, const int* in_sizes, int n_in,
                              void* d_out, int out_size, void* d_ws, size_t ws_size,
                              hipStream_t stream) {
    (void)in_sizes; (void)n_in; (void)ws_size;
    const float* x    = (const float*)d_in[0];
    const float* wihL = (const float*)d_in[1];
    const float* whhL = (const float*)d_in[2];
    const float* bihL = (const float*)d_in[3];
    const float* bhhL = (const float*)d_in[4];
    const float* wfcL = (const float*)d_in[5];
    const float* bfcL = (const float*)d_in[6];
    const float* wihR = (const float*)d_in[7];
    const float* whhR = (const float*)d_in[8];
    const float* bihR = (const float*)d_in[9];
    const float* bhhR = (const float*)d_in[10];
    const float* wfcR = (const float*)d_in[11];
    const float* bfcR = (const float*)d_in[12];

    char* ws = (char*)d_ws;
    size_t off = 0;
    auto take = [&](size_t bytes) -> char* {
        off = (off + 255) & ~(size_t)255;
        char* p = ws + off;
        off += bytes;
        return p;
    };
    bf16*     WAH = (bf16*)take((size_t)2 * WA_UNITS_DIR * 1024);  // 6 MiB
    bf16*     WAL = (bf16*)take((size_t)2 * WA_UNITS_DIR * 1024);  // 6 MiB
    bf16*     WBH = (bf16*)take((size_t)2 * WB_UNITS_DIR * 1024);  // 8 MiB
    bf16*     WBL = (bf16*)take((size_t)2 * WB_UNITS_DIR * 1024);  // 8 MiB
    bf16*     WCH = (bf16*)take((size_t)2 * WC_UNITS_DIR * 1024);  // 0.5 MiB
    bf16*     WCL = (bf16*)take((size_t)2 * WC_UNITS_DIR * 1024);  // 0.5 MiB
    bf16*     H0  = (bf16*)take((size_t)8 * HPAR * 2);             // 2 MiB (dir x parity x hi/lo)
    bf16*     H1  = (bf16*)take((size_t)8 * HPAR * 2);             // 2 MiB
    float*    WCF = (float*)take((size_t)2 * 2048 * 512 * 4);      // 8 MiB fp32 scratch
    float*    BA  = (float*)take((size_t)2 * 2048 * 4);
    float*    BB  = (float*)take((size_t)2 * 2048 * 4);
    float*    BC  = (float*)take((size_t)2 * 256 * 4);
    unsigned* FLG = (unsigned*)take((size_t)256 * 4);              // barrier flags

    hipMemsetAsync(H0, 0, (size_t)8 * HPAR * 2, stream);
    hipMemsetAsync(H1, 0, (size_t)8 * HPAR * 2, stream);
    hipMemsetAsync(FLG, 0, (size_t)256 * 4, stream);               // clear 0xAA poison!
    hipMemsetAsync(d_out, 0, (size_t)out_size * 4, stream);

    k_pack_wa<<<1536, 256, 0, stream>>>(wihL, whhL, wihR, whhR, WAH, WAL);
    k_wcomb  <<<8192, 256, 0, stream>>>(wihL, wfcL, wihR, wfcR, WCF);
    k_pack_wb<<<2048, 256, 0, stream>>>(whhL, whhR, WCF, WBH, WBL);
    k_pack_wc<<<128,  256, 0, stream>>>(wfcL, wfcR, WCH, WCL);
    k_bias   <<<16,   256, 0, stream>>>(bihL, bhhL, bfcL, wihL, bihR, bhhR, bfcR, wihR, BA, BB, BC);

    bilstm_main<<<256, 256, 0, stream>>>(x, WAH, WAL, WBH, WBL, WCH, WCL,
                                         H0, H1, BA, BB, BC, (float*)d_out, FLG);
}

// Round 6
// 28551.459 us; speedup vs baseline: 1.1674x; 1.1674x over previous
//
#include <hip/hip_runtime.h>
#include <hip/hip_bf16.h>

using bf16   = __bf16;
using bf16x8 = __attribute__((ext_vector_type(8))) __bf16;
using f32x4  = __attribute__((ext_vector_type(4))) float;
using u32x4  = __attribute__((ext_vector_type(4))) unsigned int;

#define TSTEPS 255
// element (bf16) counts
#define UNITE  512              // elements per 1KiB MFMA fragment unit
#define HPAR   (16*16*512)      // one (parity,hi-or-lo) h plane: 16 bq x 16 kb units
#define WA_UNITS_DIR (128*24)
#define WB_UNITS_DIR (128*32)
#define WC_UNITS_DIR (16*16)

#define MFMA(acc, a, b) acc = __builtin_amdgcn_mfma_f32_16x16x32_bf16((a), (b), (acc), 0, 0, 0)

__device__ __forceinline__ float sigmoidf_(float x) { return 1.f / (1.f + __expf(-x)); }
__device__ __forceinline__ float tanhf_(float x) {
    float e = __expf(-2.f * fabsf(x));
    float t = (1.f - e) / (1.f + e);
    return copysignf(t, x);
}

// Write-through coherent 2B store pair (hi, lo). sc0 sc1 -> store goes to the
// device coherent point directly, never dirty in producer L2 -> barrier
// release needs only s_waitcnt vmcnt(0), no buffer_wbl2.
__device__ __forceinline__ void storeh_coh(bf16* ph, bf16* pl,
                                           unsigned short vh, unsigned short vl) {
    asm volatile(
        "global_store_short %0, %2, off sc0 sc1\n\t"
        "global_store_short %1, %3, off sc0 sc1"
        :: "v"(ph), "v"(pl), "v"(vh), "v"(vl)
        : "memory");
}

// Coherent 32KiB global->LDS stage (hi 16KiB + lo 16KiB), 512 threads.
// 4 dwordx4 loads per thread issued back-to-back, one waitcnt, LDS writes.
__device__ __forceinline__ void stage32k_512(const bf16* gh, const bf16* gl,
                                             bf16* lds, int tid) {
    u32x4 a0, a1, b0, b1;
    const bf16* p0 = gh + tid * 8;
    const bf16* p1 = p0 + 4096;       // +8192 B
    const bf16* q0 = gl + tid * 8;
    const bf16* q1 = q0 + 4096;
    asm volatile(
        "global_load_dwordx4 %0, %4, off sc0 sc1\n\t"
        "global_load_dwordx4 %1, %5, off sc0 sc1\n\t"
        "global_load_dwordx4 %2, %6, off sc0 sc1\n\t"
        "global_load_dwordx4 %3, %7, off sc0 sc1\n\t"
        "s_waitcnt vmcnt(0)"
        : "=&v"(a0), "=&v"(a1), "=&v"(b0), "=&v"(b1)
        : "v"(p0), "v"(p1), "v"(q0), "v"(q1)
        : "memory");
    *(u32x4*)(lds + tid * 8)               = a0;   // hi plane [0, 8192)
    *(u32x4*)(lds + tid * 8 + 4096)        = a1;
    *(u32x4*)(lds + 8192 + tid * 8)        = b0;   // lo plane [8192, 16384)
    *(u32x4*)(lds + 8192 + tid * 8 + 4096) = b1;
}

// fp32x8 -> (bf16 hi, bf16 lo) x8.  lo = rnd(v - hi).
__device__ __forceinline__ void split_store8(const float* __restrict__ src,
                                             bf16* __restrict__ dh, bf16* __restrict__ dl) {
    float f[8];
    *(float4*)f       = *(const float4*)src;
    *(float4*)(f + 4) = *(const float4*)(src + 4);
    bf16x8 oh, ol;
    #pragma unroll
    for (int j = 0; j < 8; ++j) { bf16 h = (bf16)f[j]; oh[j] = h; ol[j] = (bf16)(f[j] - (float)h); }
    *(bf16x8*)dh = oh; *(bf16x8*)dl = ol;
}

// ---------------- software grid barrier (no wbl2, no cache invalidation) ----
__device__ __forceinline__ void gbarrier(unsigned* __restrict__ flags, int bid, unsigned epoch) {
    asm volatile("s_waitcnt vmcnt(0)" ::: "memory");   // release: coherent h stores done
    __syncthreads();
    if (threadIdx.x == 0)
        asm volatile("global_store_dword %0, %1, off sc0 sc1"
                     :: "v"(&flags[bid]), "v"(epoch) : "memory");
    if (threadIdx.x < 64) {
        const int l = threadIdx.x;
        for (;;) {
            unsigned f0 = __hip_atomic_load(&flags[l],       __ATOMIC_RELAXED, __HIP_MEMORY_SCOPE_AGENT);
            unsigned f1 = __hip_atomic_load(&flags[l + 64],  __ATOMIC_RELAXED, __HIP_MEMORY_SCOPE_AGENT);
            unsigned f2 = __hip_atomic_load(&flags[l + 128], __ATOMIC_RELAXED, __HIP_MEMORY_SCOPE_AGENT);
            unsigned f3 = __hip_atomic_load(&flags[l + 192], __ATOMIC_RELAXED, __HIP_MEMORY_SCOPE_AGENT);
            if (__all(f0 >= epoch && f1 >= epoch && f2 >= epoch && f3 >= epoch)) break;
            __builtin_amdgcn_s_sleep(1);
        }
    }
    __syncthreads();
}

// ---------------- precompute kernels (UNCHANGED packing) ----------------

__global__ void k_pack_wa(const float* __restrict__ wihL, const float* __restrict__ whhL,
                          const float* __restrict__ wihR, const float* __restrict__ whhR,
                          bf16* __restrict__ wah, bf16* __restrict__ wal) {
    int gid = blockIdx.x * 256 + threadIdx.x;      // 393,216
    int lane = gid & 63, u = gid >> 6;             // u < 6144
    int kb = u % 24; int tn = (u / 24) & 127; int dir = u / 3072;
    int r = lane & 15, q = lane >> 4;
    int n = tn * 16 + r, k = kb * 32 + q * 8;
    const float* wih = dir ? wihR : wihL;          // layer 0 slice at offset 0
    const float* whh = dir ? whhR : whhL;
    const float* src = (k < 256) ? (wih + (size_t)n * 256 + k)
                                 : (whh + (size_t)n * 512 + (k - 256));
    split_store8(src, wah + (size_t)u * UNITE + lane * 8, wal + (size_t)u * UNITE + lane * 8);
}

__global__ void k_wcomb(const float* __restrict__ wihL, const float* __restrict__ wfcL,
                        const float* __restrict__ wihR, const float* __restrict__ wfcR,
                        float* __restrict__ wcf) {
    size_t gid = (size_t)blockIdx.x * 256 + threadIdx.x;  // 2,097,152
    int k = gid & 511; int n = (gid >> 9) & 2047; int dir = (int)(gid >> 20);
    const float* wih1 = (dir ? wihR : wihL) + (size_t)2048 * 256;  // layer 1
    const float* wfc0 = (dir ? wfcR : wfcL);                        // layer 0
    float s = 0.f;
    #pragma unroll 8
    for (int v = 0; v < 256; ++v)
        s = fmaf(wih1[(size_t)n * 256 + v], wfc0[(size_t)v * 512 + k], s);
    wcf[gid] = s;
}

__global__ void k_pack_wb(const float* __restrict__ whhL, const float* __restrict__ whhR,
                          const float* __restrict__ wcf,
                          bf16* __restrict__ wbh, bf16* __restrict__ wbl) {
    int gid = blockIdx.x * 256 + threadIdx.x;      // 524,288
    int lane = gid & 63, u = gid >> 6;             // u < 8192
    int kb = u & 31, tn = (u >> 5) & 127, dir = u >> 12;
    int r = lane & 15, q = lane >> 4;
    int n = tn * 16 + r, k = kb * 32 + q * 8;
    const float* src;
    if (k < 512) {
        src = wcf + ((size_t)dir * 2048 + n) * 512 + k;
    } else {
        const float* whh1 = (dir ? whhR : whhL) + (size_t)2048 * 512;
        src = whh1 + (size_t)n * 512 + (k - 512);
    }
    split_store8(src, wbh + (size_t)u * UNITE + lane * 8, wbl + (size_t)u * UNITE + lane * 8);
}

__global__ void k_pack_wc(const float* __restrict__ wfcL, const float* __restrict__ wfcR,
                          bf16* __restrict__ wch, bf16* __restrict__ wcl) {
    int gid = blockIdx.x * 256 + threadIdx.x;      // 32,768
    int lane = gid & 63, u = gid >> 6;             // u < 512
    int kb = u & 15, tn = (u >> 4) & 15, dir = u >> 8;
    int r = lane & 15, q = lane >> 4;
    int n = tn * 16 + r, k = kb * 32 + q * 8;
    const float* wfc1 = (dir ? wfcR : wfcL) + (size_t)256 * 512;   // layer 1
    split_store8(wfc1 + (size_t)n * 512 + k,
                 wch + (size_t)u * UNITE + lane * 8, wcl + (size_t)u * UNITE + lane * 8);
}

__global__ void k_bias(const float* __restrict__ bihL, const float* __restrict__ bhhL,
                       const float* __restrict__ bfcL, const float* __restrict__ wihL,
                       const float* __restrict__ bihR, const float* __restrict__ bhhR,
                       const float* __restrict__ bfcR, const float* __restrict__ wihR,
                       float* __restrict__ ba, float* __restrict__ bb, float* __restrict__ bc) {
    int gid = blockIdx.x * 256 + threadIdx.x;      // 4096
    int n = gid & 2047, dir = gid >> 11;
    const float* bih = dir ? bihR : bihL;
    const float* bhh = dir ? bhhR : bhhL;
    const float* bfc = dir ? bfcR : bfcL;
    const float* wih1 = (dir ? wihR : wihL) + (size_t)2048 * 256;
    ba[dir * 2048 + n] = bih[n] + bhh[n];
    float s = bih[2048 + n] + bhh[2048 + n];
    #pragma unroll 8
    for (int v = 0; v < 256; ++v)
        s = fmaf(bfc[v], wih1[(size_t)n * 256 + v], s);
    bb[dir * 2048 + n] = s;
    if (n < 256) bc[dir * 256 + n] = bfc[256 + n];
}

// ---------------- main persistent kernel ----------------
// R6: 512-thread blocks (8 waves), K-SPLIT across wave-groups kg=wv>>2:
// same per-CU weight bytes, 2x wave-level memory parallelism (theory: phase
// time is load-latency-bound at 4 waves/CU; dur was invariant to all traffic
// changes R1-R5 while machine sat ~94% idle).
//   kg0 computes low-K partial, kg1 high-K partial -> LDS reduce -> kg0 does
//   elementwise + coherent h store. y-GEMM handled entirely by kg1 (4 waves:
//   2 tn x 2 K-halves, small LDS reduce).
// Block = (dir, nslc 0..7, bq 0..15) as R3; 1 block/CU (82 KB LDS) keeps
// sw-barrier co-residency. nt hints reverted (R5: hurt).
__global__ __launch_bounds__(512) void bilstm_main(
    const float* __restrict__ x,
    const bf16* __restrict__ wah, const bf16* __restrict__ wal,
    const bf16* __restrict__ wbh, const bf16* __restrict__ wbl,
    const bf16* __restrict__ wch, const bf16* __restrict__ wcl,
    bf16* __restrict__ h0pk, bf16* __restrict__ h1pk,
    const float* __restrict__ ba, const float* __restrict__ bb,
    const float* __restrict__ bc, float* __restrict__ out,
    unsigned* __restrict__ flags)
{
    const int bid  = blockIdx.x;
    const int nslc = bid & 7;            // == XCD (bid%8 heuristic)
    const int bq   = (bid >> 3) & 15;    // batch-row slice
    const int dir  = bid >> 7;
    const int tid  = threadIdx.x;
    const int wv   = tid >> 6;
    const int wq   = wv & 3;             // virtual wave (old wv role)
    const int kg   = wv >> 2;            // K-group
    const int lane = tid & 63;
    const int r = lane & 15, q = lane >> 4;

    __shared__ __align__(16) bf16 h0s[16384];      // 32 KiB
    __shared__ __align__(16) bf16 h1s[16384];      // 32 KiB
    __shared__ __align__(16) float gred[4][4][64][4];  // 16 KiB: [wq][g][lane][i]
    __shared__ __align__(16) float yred[2][64][4];     // 2 KiB

    const bf16* WAh = wah + (size_t)dir * WA_UNITS_DIR * UNITE;
    const bf16* WAl = wal + (size_t)dir * WA_UNITS_DIR * UNITE;
    const bf16* WBh = wbh + (size_t)dir * WB_UNITS_DIR * UNITE;
    const bf16* WBl = wbl + (size_t)dir * WB_UNITS_DIR * UNITE;
    const bf16* WCh = wch + (size_t)dir * WC_UNITS_DIR * UNITE;
    const bf16* WCl = wcl + (size_t)dir * WC_UNITS_DIR * UNITE;
    bf16* H0 = h0pk + (size_t)dir * 4 * HPAR;   // [parity][hi/lo][HPAR]
    bf16* H1 = h1pk + (size_t)dir * 4 * HPAR;
    const float* BA = ba + dir * 2048;
    const float* BB = bb + dir * 2048;
    const float* BC = bc + dir * 256;

    const int nbase = nslc * 4 + wq;             // n-unit (16 gate cols) per virtual wave
    const int col   = nslc * 64 + wq * 16 + r;   // hidden col this lane owns
    const float bia0 = BA[col], bia1 = BA[512 + col], bia2 = BA[1024 + col], bia3 = BA[1536 + col];
    const float bib0 = BB[col], bib1 = BB[512 + col], bib2 = BB[1024 + col], bib3 = BB[1536 + col];

    // h write address (kg0 only): unit = bq*16 + (col>>5); within-unit offset
    const int hunit  = bq * 16 + nslc * 2 + (wq >> 1);
    const int hw_off = ((wq & 1) * 2 + (r >> 3)) * 128 + q * 32 + (r & 7);

    // y-tile (kg1): tn by wq&1, K-half by wq>>1
    const int tn  = nslc * 2 + (wq & 1);
    const float byc = BC[tn * 16 + r];

    f32x4 c0 = {0.f, 0.f, 0.f, 0.f}, c1 = {0.f, 0.f, 0.f, 0.f};
    unsigned epoch = 0;

    // zero h0s (h0 at t=-1 is zero): 512 threads x 8 elems x 4 rounds
    #pragma unroll
    for (int k2 = 0; k2 < 4; ++k2) *(u32x4*)(h0s + tid * 8 + k2 * 4096) = (u32x4){0, 0, 0, 0};
    __syncthreads();

    for (int t = 0; t <= TSTEPS; ++t) {
        const int pw = t & 1, pr = pw ^ 1;
        // ---- S1: stage h1[pr]; partial gates0 ----
        stage32k_512(H1 + (size_t)pr * 2 * HPAR + (size_t)bq * 8192,
                     H1 + (size_t)pr * 2 * HPAR + HPAR + (size_t)bq * 8192, h1s, tid);
        f32x4 acc[4] = {{0,0,0,0},{0,0,0,0},{0,0,0,0},{0,0,0,0}};
        if (t < TSTEPS) {
            if (kg == 0) {
                const int pos = dir ? (255 - t) : t;
                const float* xp = x + ((size_t)(bq * 16 + r) * 256 + pos) * 256 + q * 8;
                #pragma unroll
                for (int kb = 0; kb < 8; ++kb) {        // x part (K 0..255)
                    float xf[8];
                    *(float4*)xf       = *(const float4*)(xp + kb * 32);
                    *(float4*)(xf + 4) = *(const float4*)(xp + kb * 32 + 4);
                    bf16x8 axh, axl;
                    #pragma unroll
                    for (int j = 0; j < 8; ++j) { bf16 h = (bf16)xf[j]; axh[j] = h; axl[j] = (bf16)(xf[j] - (float)h); }
                    #pragma unroll
                    for (int g = 0; g < 4; ++g) {
                        const size_t wu = ((size_t)((g * 32 + nbase) * 24 + kb)) * UNITE + lane * 8;
                        bf16x8 bh = *(const bf16x8*)(WAh + wu);
                        bf16x8 bl = *(const bf16x8*)(WAl + wu);
                        MFMA(acc[g], axh, bh); MFMA(acc[g], axh, bl); MFMA(acc[g], axl, bh);
                    }
                }
                #pragma unroll
                for (int hk = 0; hk < 4; ++hk) {        // h0(t-1) low kb
                    bf16x8 ah = *(const bf16x8*)(h0s + hk * 512 + lane * 8);
                    bf16x8 al = *(const bf16x8*)(h0s + 8192 + hk * 512 + lane * 8);
                    #pragma unroll
                    for (int g = 0; g < 4; ++g) {
                        const size_t wu = ((size_t)((g * 32 + nbase) * 24 + 8 + hk)) * UNITE + lane * 8;
                        bf16x8 bh = *(const bf16x8*)(WAh + wu);
                        bf16x8 bl = *(const bf16x8*)(WAl + wu);
                        MFMA(acc[g], ah, bh); MFMA(acc[g], ah, bl); MFMA(acc[g], al, bh);
                    }
                }
            } else {
                #pragma unroll
                for (int hk = 4; hk < 16; ++hk) {       // h0(t-1) high kb
                    bf16x8 ah = *(const bf16x8*)(h0s + hk * 512 + lane * 8);
                    bf16x8 al = *(const bf16x8*)(h0s + 8192 + hk * 512 + lane * 8);
                    #pragma unroll
                    for (int g = 0; g < 4; ++g) {
                        const size_t wu = ((size_t)((g * 32 + nbase) * 24 + 8 + hk)) * UNITE + lane * 8;
                        bf16x8 bh = *(const bf16x8*)(WAh + wu);
                        bf16x8 bl = *(const bf16x8*)(WAl + wu);
                        MFMA(acc[g], ah, bh); MFMA(acc[g], ah, bl); MFMA(acc[g], al, bh);
                    }
                }
                #pragma unroll
                for (int g = 0; g < 4; ++g) *(f32x4*)&gred[wq][g][lane][0] = acc[g];
            }
        }
        __syncthreads();   // SYNC1: h1s staged; gred visible
        // ---- S2: kg0 finish gates0; kg1 partial y ----
        if (t < TSTEPS && kg == 0) {
            bf16* WH = H0 + (size_t)pw * 2 * HPAR + (size_t)hunit * 512 + hw_off;
            bf16* WL = WH + HPAR;
            #pragma unroll
            for (int i = 0; i < 4; ++i) {
                float gi = sigmoidf_(acc[0][i] + gred[wq][0][lane][i] + bia0);
                float gf = sigmoidf_(acc[1][i] + gred[wq][1][lane][i] + bia1);
                float gg = tanhf_   (acc[2][i] + gred[wq][2][lane][i] + bia2);
                float go = sigmoidf_(acc[3][i] + gred[wq][3][lane][i] + bia3);
                float cc = gf * c0[i] + gi * gg;
                c0[i] = cc;
                float hv = go * tanhf_(cc);
                bf16 hh = (bf16)hv;
                bf16 hl = (bf16)(hv - (float)hh);
                storeh_coh(WH + i * 8, WL + i * 8,
                           __builtin_bit_cast(unsigned short, hh),
                           __builtin_bit_cast(unsigned short, hl));
            }
        }
        f32x4 accy = {0, 0, 0, 0};
        if (t >= 1 && kg == 1) {
            const int kb0 = (wq >> 1) * 8;
            #pragma unroll
            for (int kk = 0; kk < 8; ++kk) {
                const int kb = kb0 + kk;
                bf16x8 ah = *(const bf16x8*)(h1s + kb * 512 + lane * 8);
                bf16x8 al = *(const bf16x8*)(h1s + 8192 + kb * 512 + lane * 8);
                const size_t wu = ((size_t)(tn * 16 + kb)) * UNITE + lane * 8;
                bf16x8 bh = *(const bf16x8*)(WCh + wu);
                bf16x8 bl = *(const bf16x8*)(WCl + wu);
                MFMA(accy, ah, bh); MFMA(accy, ah, bl); MFMA(accy, al, bh);
            }
            if (wq >= 2) *(f32x4*)&yred[wq & 1][lane][0] = accy;
        }
        __syncthreads();   // SYNC2: yred visible
        // ---- S3: kg1 wq0,1 finish y ----
        if (t >= 1 && kg == 1 && wq < 2) {
            const int tout = dir ? (255 + (t - 1)) : (t - 1);
            #pragma unroll
            for (int i = 0; i < 4; ++i)
                out[((size_t)(bq * 16 + 4 * q + i) * 510 + tout) * 256 + tn * 16 + r]
                    = accy[i] + yred[wq][lane][i] + byc;
        }
        ++epoch; gbarrier(flags, bid, epoch);
        // ---- phase B ----
        if (t < TSTEPS) {
            stage32k_512(H0 + (size_t)pw * 2 * HPAR + (size_t)bq * 8192,
                         H0 + (size_t)pw * 2 * HPAR + HPAR + (size_t)bq * 8192, h0s, tid);
            __syncthreads();   // SYNC3: h0s ready (stays valid for next step's phase A)
            f32x4 accb[4] = {{0,0,0,0},{0,0,0,0},{0,0,0,0},{0,0,0,0}};
            if (kg == 0) {
                #pragma unroll
                for (int hk = 0; hk < 16; ++hk) {       // h0(t) part (K 0..511)
                    bf16x8 ah = *(const bf16x8*)(h0s + hk * 512 + lane * 8);
                    bf16x8 al = *(const bf16x8*)(h0s + 8192 + hk * 512 + lane * 8);
                    #pragma unroll
                    for (int g = 0; g < 4; ++g) {
                        const size_t wu = ((size_t)((g * 32 + nbase) * 32 + hk)) * UNITE + lane * 8;
                        bf16x8 bh = *(const bf16x8*)(WBh + wu);
                        bf16x8 bl = *(const bf16x8*)(WBl + wu);
                        MFMA(accb[g], ah, bh); MFMA(accb[g], ah, bl); MFMA(accb[g], al, bh);
                    }
                }
            } else {
                #pragma unroll
                for (int hk = 0; hk < 16; ++hk) {       // h1(t-1) part (K 512..1023)
                    bf16x8 ah = *(const bf16x8*)(h1s + hk * 512 + lane * 8);
                    bf16x8 al = *(const bf16x8*)(h1s + 8192 + hk * 512 + lane * 8);
                    #pragma unroll
                    for (int g = 0; g < 4; ++g) {
                        const size_t wu = ((size_t)((g * 32 + nbase) * 32 + 16 + hk)) * UNITE + lane * 8;
                        bf16x8 bh = *(const bf16x8*)(WBh + wu);
                        bf16x8 bl = *(const bf16x8*)(WBl + wu);
                        MFMA(accb[g], ah, bh); MFMA(accb[g], ah, bl); MFMA(accb[g], al, bh);
                    }
                }
                #pragma unroll
                for (int g = 0; g < 4; ++g) *(f32x4*)&gred[wq][g][lane][0] = accb[g];
            }
            __syncthreads();   // SYNC4: gred visible
            if (kg == 0) {
                bf16* WH = H1 + (size_t)pw * 2 * HPAR + (size_t)hunit * 512 + hw_off;
                bf16* WL = WH + HPAR;
                #pragma unroll
                for (int i = 0; i < 4; ++i) {
                    float gi = sigmoidf_(accb[0][i] + gred[wq][0][lane][i] + bib0);
                    float gf = sigmoidf_(accb[1][i] + gred[wq][1][lane][i] + bib1);
                    float gg = tanhf_   (accb[2][i] + gred[wq][2][lane][i] + bib2);
                    float go = sigmoidf_(accb[3][i] + gred[wq][3][lane][i] + bib3);
                    float cc = gf * c1[i] + gi * gg;
                    c1[i] = cc;
                    float hv = go * tanhf_(cc);
                    bf16 hh = (bf16)hv;
                    bf16 hl = (bf16)(hv - (float)hh);
                    storeh_coh(WH + i * 8, WL + i * 8,
                               __builtin_bit_cast(unsigned short, hh),
                               __builtin_bit_cast(unsigned short, hl));
                }
            }
        }
        ++epoch; gbarrier(flags, bid, epoch);
    }
}

// ---------------- host launch ----------------
extern "C" void kernel_launch(void* const* d_in, const int* in_sizes, int n_in,
                              void* d_out, int out_size, void* d_ws, size_t ws_size,
                              hipStream_t stream) {
    (void)in_sizes; (void)n_in; (void)ws_size;
    const float* x    = (const float*)d_in[0];
    const float* wihL = (const float*)d_in[1];
    const float* whhL = (const float*)d_in[2];
    const float* bihL = (const float*)d_in[3];
    const float* bhhL = (const float*)d_in[4];
    const float* wfcL = (const float*)d_in[5];
    const float* bfcL = (const float*)d_in[6];
    const float* wihR = (const float*)d_in[7];
    const float* whhR = (const float*)d_in[8];
    const float* bihR = (const float*)d_in[9];
    const float* bhhR = (const float*)d_in[10];
    const float* wfcR = (const float*)d_in[11];
    const float* bfcR = (const float*)d_in[12];

    char* ws = (char*)d_ws;
    size_t off = 0;
    auto take = [&](size_t bytes) -> char* {
        off = (off + 255) & ~(size_t)255;
        char* p = ws + off;
        off += bytes;
        return p;
    };
    bf16*     WAH = (bf16*)take((size_t)2 * WA_UNITS_DIR * 1024);  // 6 MiB
    bf16*     WAL = (bf16*)take((size_t)2 * WA_UNITS_DIR * 1024);  // 6 MiB
    bf16*     WBH = (bf16*)take((size_t)2 * WB_UNITS_DIR * 1024);  // 8 MiB
    bf16*     WBL = (bf16*)take((size_t)2 * WB_UNITS_DIR * 1024);  // 8 MiB
    bf16*     WCH = (bf16*)take((size_t)2 * WC_UNITS_DIR * 1024);  // 0.5 MiB
    bf16*     WCL = (bf16*)take((size_t)2 * WC_UNITS_DIR * 1024);  // 0.5 MiB
    bf16*     H0  = (bf16*)take((size_t)8 * HPAR * 2);             // 2 MiB (dir x parity x hi/lo)
    bf16*     H1  = (bf16*)take((size_t)8 * HPAR * 2);             // 2 MiB
    float*    WCF = (float*)take((size_t)2 * 2048 * 512 * 4);      // 8 MiB fp32 scratch
    float*    BA  = (float*)take((size_t)2 * 2048 * 4);
    float*    BB  = (float*)take((size_t)2 * 2048 * 4);
    float*    BC  = (float*)take((size_t)2 * 256 * 4);
    unsigned* FLG = (unsigned*)take((size_t)256 * 4);              // barrier flags

    hipMemsetAsync(H0, 0, (size_t)8 * HPAR * 2, stream);
    hipMemsetAsync(H1, 0, (size_t)8 * HPAR * 2, stream);
    hipMemsetAsync(FLG, 0, (size_t)256 * 4, stream);               // clear 0xAA poison!
    hipMemsetAsync(d_out, 0, (size_t)out_size * 4, stream);

    k_pack_wa<<<1536, 256, 0, stream>>>(wihL, whhL, wihR, whhR, WAH, WAL);
    k_wcomb  <<<8192, 256, 0, stream>>>(wihL, wfcL, wihR, wfcR, WCF);
    k_pack_wb<<<2048, 256, 0, stream>>>(whhL, whhR, WCF, WBH, WBL);
    k_pack_wc<<<128,  256, 0, stream>>>(wfcL, wfcR, WCH, WCL);
    k_bias   <<<16,   256, 0, stream>>>(bihL, bhhL, bfcL, wihL, bihR, bhhR, bfcR, wihR, BA, BB, BC);

    bilstm_main<<<256, 512, 0, stream>>>(x, WAH, WAL, WBH, WBL, WCH, WCL,
                                         H0, H1, BA, BB, BC, (float*)d_out, FLG);
}